// Round 3
// baseline (416.786 us; speedup 1.0000x reference)
//
#include <hip/hip_runtime.h>
#include <math.h>

#define DIM 2048
#define SLOTS 256
#define TSTEPS 64
#define FB (TSTEPS * DIM)          // 131072 floats
#define KQ 8                       // K-split factor: K/block = 256
#define KS (DIM / KQ)              // 256 k-cols per block
#define BK 64                      // k-chunk per compute iteration
#define NC (KS / BK)               // 4 chunks
#define JG 32                      // j-cols per block (2 tiles of 16)

typedef unsigned short u16;
typedef __bf16 bf16x8 __attribute__((ext_vector_type(8)));
typedef float f32x4 __attribute__((ext_vector_type(4)));

union FragU { unsigned u[4]; bf16x8 v; };

__device__ __forceinline__ u16 f2bf(float f){
    union { float f; unsigned u; } v; v.f = f;
    unsigned r = v.u + 0x7fffu + ((v.u >> 16) & 1u);
    return (u16)(r >> 16);
}
__device__ __forceinline__ float sigmoidf_(float x){ return 1.0f / (1.0f + __expf(-x)); }

__device__ __forceinline__ void split8t(const float* x, bf16x8& hi, bf16x8& lo){
    FragU H, L;
    #pragma unroll
    for (int p = 0; p < 4; ++p){
        union { float f; unsigned u; } u0, u1, l0, l1;
        u0.f = x[2*p]; u1.f = x[2*p+1];
        unsigned h0 = u0.u & 0xffff0000u, h1 = u1.u & 0xffff0000u;
        H.u[p] = (h0 >> 16) | h1;
        l0.f = u0.f - __uint_as_float(h0);
        l1.f = u1.f - __uint_as_float(h1);
        L.u[p] = (l0.u >> 16) | (l1.u & 0xffff0000u);
    }
    hi = H.v; lo = L.v;
}

__device__ __forceinline__ f32x4 mfma16(bf16x8 a, bf16x8 b, f32x4 c){
    return __builtin_amdgcn_mfma_f32_16x16x32_bf16(a, b, c, 0, 0, 0);
}

// async global->LDS, 16B/lane; lds base wave-uniform, lane i lands at +i*16
__device__ __forceinline__ void gl_lds16(const float* gp, float* lp){
    __builtin_amdgcn_global_load_lds(
        (const __attribute__((address_space(1))) unsigned int*)gp,
        (__attribute__((address_space(3))) unsigned int*)lp, 16, 0, 0);
}

// ---- inline MFMA D-layout calibration (2 MFMAs, per block) ----
__device__ __forceinline__ void calib_inline(int lane, int w, int* trr, int* jrr){
    const u16 oneb = 0x3F80;
    const u16 lb = f2bf((float)((lane & 15) + 1));
    FragU O, L;
    #pragma unroll
    for (int p = 0; p < 4; ++p){
        O.u[p] = ((unsigned)oneb) | (((unsigned)oneb) << 16);
        L.u[p] = ((unsigned)lb)   | (((unsigned)lb)   << 16);
    }
    f32x4 z = {0.f, 0.f, 0.f, 0.f};
    f32x4 dj = mfma16(O.v, L.v, z);
    f32x4 dt = mfma16(L.v, O.v, z);
    #pragma unroll
    for (int r = 0; r < 4; ++r){
        int jl = (int)(dj[r] * (1.0f/32.0f) + 0.5f) - 1;
        int tl = (int)(dt[r] * (1.0f/32.0f) + 0.5f) - 1;
        trr[r] = w * 16 + (tl & 15);
        jrr[r] = jl & 15;
    }
}

// LDS: A-slice [4 chunks][64 rows][BK] (64 KB, staged once) + W ring 2x[16][BK] (8 KB).
struct GSm { float A[NC * 64 * BK]; float Wb[2][16 * BK]; };

__device__ __forceinline__ const float* waddr(const float* Wg0, int kbase, int chunk,
                                              int w, int rsub, int s){
    const int rowL = w * 4 + rsub;           // 0..15
    const int nj = chunk >> 2, ncc = chunk & 3;
    return Wg0 + (size_t)(nj * 16 + rowL) * DIM + kbase + ncc * BK + ((s ^ rowL) << 2);
}

// ---------------- A-resident, reg-staged 2-deep W-pipelined GEMM core ----------------
// GATHER=1: A-slice computed on the fly from traces[idx]+0.01*noise (stage-1 fusion).
template<int GATHER>
__device__ __forceinline__ void gemm_core(const float* __restrict__ A,
    const float* __restrict__ traces, const float* __restrict__ noise,
    const int* __restrict__ idxw, int i64f,
    const float* __restrict__ Wg0, int kq, GSm& sm, f32x4* acc)
{
    const int tid = threadIdx.x;
    const int lane = tid & 63, w = tid >> 6;
    const int s = lane & 15, rsub = lane >> 4;
    const int n4 = lane & 15;
    const int kbase = kq * KS;

    // ---- A-stage (once) ----
    if (GATHER){
        #pragma unroll
        for (int i = 0; i < 4; ++i){
            const int rowL = w * 16 + i * 4 + rsub;
            long rg = i64f ? (long)idxw[2 * rowL] : (long)idxw[rowL];
            const float* tp = traces + (size_t)rg * DIM + kbase + ((s ^ (rowL & 15)) << 2);
            const float* np = noise + (size_t)rowL * DIM + kbase + ((s ^ (rowL & 15)) << 2);
            #pragma unroll
            for (int c = 0; c < NC; ++c){
                float4 tv = *(const float4*)(tp + c * BK);
                float4 nv = *(const float4*)(np + c * BK);
                float4 r;
                r.x = fmaf(0.01f, nv.x, tv.x); r.y = fmaf(0.01f, nv.y, tv.y);
                r.z = fmaf(0.01f, nv.z, tv.z); r.w = fmaf(0.01f, nv.w, tv.w);
                *(float4*)&sm.A[(c * 64 + rowL) * BK + s * 4] = r;
            }
        }
    } else {
        #pragma unroll
        for (int c = 0; c < NC; ++c)
            #pragma unroll
            for (int i = 0; i < 4; ++i){
                const int rowL = w * 16 + i * 4 + rsub;
                const float* gp = A + (size_t)rowL * DIM + kbase + c * BK + ((s ^ (rowL & 15)) << 2);
                gl_lds16(gp, sm.A + (c * 64 + w * 16 + i * 4) * BK);
            }
    }
    // ---- W prologue: chunks 0,1 into regs ----
    float4 wr0 = *(const float4*)waddr(Wg0, kbase, 0, w, rsub, s);
    float4 wr1 = *(const float4*)waddr(Wg0, kbase, 1, w, rsub, s);
    __syncthreads();            // full drain once: A staged, wr0/wr1 in regs

    acc[0] = (f32x4){0.f, 0.f, 0.f, 0.f};
    acc[1] = (f32x4){0.f, 0.f, 0.f, 0.f};

    // 8 chunk-iterations; write W chunk it from reg, reload reg with chunk it+2
    // (plain VMEM loads stay in flight across the raw barrier — no vmcnt drain).
    #pragma unroll
    for (int it = 0; it < 2 * NC; ++it){
        const int slot = it & 1;
        if (slot == 0){
            *(float4*)&sm.Wb[0][(w * 4 + rsub) * BK + s * 4] = wr0;
            if (it + 2 < 2 * NC)
                wr0 = *(const float4*)waddr(Wg0, kbase, it + 2, w, rsub, s);
        } else {
            *(float4*)&sm.Wb[1][(w * 4 + rsub) * BK + s * 4] = wr1;
            if (it + 2 < 2 * NC)
                wr1 = *(const float4*)waddr(Wg0, kbase, it + 2, w, rsub, s);
        }
        asm volatile("s_waitcnt lgkmcnt(0)\n\ts_barrier" ::: "memory");
        const int jt = it >> 2, c = it & 3;
        const float* At = sm.A + c * 64 * BK;
        const float* Wt = sm.Wb[slot];
        #pragma unroll
        for (int ks = 0; ks < 2; ++ks){
            const int cg0 = ks * 8 + (lane >> 4) * 2;
            const int rA = w * 16 + n4;
            float a8[8], w8[8];
            *(float4*)(a8)     = *(const float4*)&At[rA * BK + ((cg0 ^ n4) << 2)];
            *(float4*)(a8 + 4) = *(const float4*)&At[rA * BK + (((cg0 + 1) ^ n4) << 2)];
            *(float4*)(w8)     = *(const float4*)&Wt[n4 * BK + ((cg0 ^ n4) << 2)];
            *(float4*)(w8 + 4) = *(const float4*)&Wt[n4 * BK + (((cg0 + 1) ^ n4) << 2)];
            bf16x8 ah, al, wh, wl;
            split8t(a8, ah, al);
            split8t(w8, wh, wl);
            if (jt == 0){
                acc[0] = mfma16(ah, wh, acc[0]);
                acc[0] = mfma16(al, wh, acc[0]);
                acc[0] = mfma16(ah, wl, acc[0]);
            } else {
                acc[1] = mfma16(ah, wh, acc[1]);
                acc[1] = mfma16(al, wh, acc[1]);
                acc[1] = mfma16(ah, wl, acc[1]);
            }
        }
        asm volatile("s_barrier" ::: "memory");  // reads done before next overwrite
    }
}

// stage-1 GEMM with fused gather/noise prep: grid = 64 jg x 8 kq
__global__ __launch_bounds__(256)
void gemm_g1(const float* __restrict__ traces, const float* __restrict__ noise,
             const int* __restrict__ idxw, const float* __restrict__ W,
             float* __restrict__ Pp)
{
    __shared__ GSm sm;
    __shared__ int i64f_s;
    const int tid = threadIdx.x;
    int v = 0;
    if (tid < 32) v = (idxw[2 * tid + 1] != 0) ? 1 : 0;
    unsigned long long bm = __ballot(v);
    if (tid == 0) i64f_s = (bm == 0ull) ? 1 : 0;
    __syncthreads();
    const int i64f = i64f_s;

    const int kq = blockIdx.x & (KQ - 1);
    const int jg = blockIdx.x >> 3;
    const int j0 = jg * JG;
    const int lane = tid & 63, w = tid >> 6;
    int trr[4], jrr[4];
    calib_inline(lane, w, trr, jrr);
    f32x4 acc[2];
    gemm_core<1>(nullptr, traces, noise, idxw, i64f, W + (size_t)j0 * DIM, kq, sm, acc);
    float* outb = Pp + (size_t)kq * FB;
    #pragma unroll
    for (int jt = 0; jt < 2; ++jt)
        #pragma unroll
        for (int r = 0; r < 4; ++r)
            outb[(size_t)trr[r] * DIM + j0 + jt * 16 + jrr[r]] = acc[jt][r];
}

// stage GEMM: grid = 64 jg x 8 kq = 512
__global__ __launch_bounds__(256)
void gemm_s(const float* __restrict__ A, const float* __restrict__ W,
            float* __restrict__ Pp)
{
    __shared__ GSm sm;
    const int kq = blockIdx.x & (KQ - 1);
    const int jg = blockIdx.x >> 3;
    const int j0 = jg * JG;
    const int lane = threadIdx.x & 63, w = threadIdx.x >> 6;
    int trr[4], jrr[4];
    calib_inline(lane, w, trr, jrr);
    f32x4 acc[2];
    gemm_core<0>(A, nullptr, nullptr, nullptr, 0, W + (size_t)j0 * DIM, kq, sm, acc);
    float* outb = Pp + (size_t)kq * FB;
    #pragma unroll
    for (int jt = 0; jt < 2; ++jt)
        #pragma unroll
        for (int r = 0; r < 4; ++r)
            outb[(size_t)trr[r] * DIM + j0 + jt * 16 + jrr[r]] = acc[jt][r];
}

// heads GEMM: grid = (64 We + 64 Wad + 8 Wa) x 8 kq = 1088
__global__ __launch_bounds__(256)
void gemm_h(const float* __restrict__ G,
            const float* __restrict__ We, const float* __restrict__ Wad,
            const float* __restrict__ Wa,
            float* __restrict__ PpE, float* __restrict__ PpA, float* __restrict__ PpL)
{
    __shared__ GSm sm;
    const int kq = blockIdx.x & (KQ - 1);
    const int jg = blockIdx.x >> 3;
    const float* W; float* out; int j0, NJ;
    if (jg < 64)       { W = We;  out = PpE; j0 = jg * JG;        NJ = DIM; }
    else if (jg < 128) { W = Wad; out = PpA; j0 = (jg - 64) * JG; NJ = DIM; }
    else               { W = Wa;  out = PpL; j0 = (jg - 128) * JG; NJ = SLOTS; }
    const int lane = threadIdx.x & 63, w = threadIdx.x >> 6;
    int trr[4], jrr[4];
    calib_inline(lane, w, trr, jrr);
    f32x4 acc[2];
    gemm_core<0>(G, nullptr, nullptr, nullptr, 0, W + (size_t)j0 * DIM, kq, sm, acc);
    float* outb = out + (size_t)kq * 64 * NJ;
    #pragma unroll
    for (int jt = 0; jt < 2; ++jt)
        #pragma unroll
        for (int r = 0; r < 4; ++r)
            outb[(size_t)trr[r] * NJ + j0 + jt * 16 + jrr[r]] = acc[jt][r];
}

// ---------------- combine 8 partials + bias + activation (NJ = DIM) ----------------
// MODE 0: relu  1: plain  2: sig(u)*sig(ps*vw+vb)  3: X*sig(u)
template<int MODE>
__global__ __launch_bounds__(256)
void comb8(const float* __restrict__ P, const float* __restrict__ bias,
           const float* __restrict__ vwp, const float* __restrict__ vbp,
           const float* __restrict__ Xp, float* __restrict__ out)
{
    const size_t i0 = ((size_t)blockIdx.x * 256 + threadIdx.x) * 8;
    const int t = (int)(i0 >> 11);
    const int j = (int)(i0 & (DIM - 1));
    float v[8], tmp[8];
    *(float4*)(v)     = *(const float4*)(P + i0);
    *(float4*)(v + 4) = *(const float4*)(P + i0 + 4);
    #pragma unroll
    for (int p = 1; p < KQ; ++p){
        *(float4*)(tmp)     = *(const float4*)(P + (size_t)p * FB + i0);
        *(float4*)(tmp + 4) = *(const float4*)(P + (size_t)p * FB + i0 + 4);
        #pragma unroll
        for (int c = 0; c < 8; ++c) v[c] += tmp[c];
    }
    float b8[8];
    *(float4*)(b8)     = *(const float4*)(bias + j);
    *(float4*)(b8 + 4) = *(const float4*)(bias + j + 4);
    float x8[8], y8[8];
    if (MODE == 2){
        *(float4*)(x8)     = *(const float4*)(vwp + j);
        *(float4*)(x8 + 4) = *(const float4*)(vwp + j + 4);
        *(float4*)(y8)     = *(const float4*)(vbp + j);
        *(float4*)(y8 + 4) = *(const float4*)(vbp + j + 4);
    }
    if (MODE == 3){
        *(float4*)(x8)     = *(const float4*)(Xp + i0);
        *(float4*)(x8 + 4) = *(const float4*)(Xp + i0 + 4);
    }
    const float ps = -cosf(0.37699111843077515f * (float)(t + 1));
    float r[8];
    #pragma unroll
    for (int c = 0; c < 8; ++c){
        float u = v[c] + b8[c];
        if (MODE == 0)      r[c] = fmaxf(u, 0.f);
        else if (MODE == 1) r[c] = u;
        else if (MODE == 2) r[c] = sigmoidf_(u) * sigmoidf_(fmaf(ps, x8[c], y8[c]));
        else                r[c] = x8[c] * sigmoidf_(u);
    }
    *(float4*)(out + i0)     = *(const float4*)(r);
    *(float4*)(out + i0 + 4) = *(const float4*)(r + 4);
}

// -------- fused: scan (wave 0, redundant per block) + E/A combine + recurrence -------
// grid = DIM/8 = 256 blocks x 256 threads; LDS wg[64][256] = 64 KB.
__global__ __launch_bounds__(256)
void memscan_k(const float* __restrict__ PpL, const float* __restrict__ ba,
               const float* __restrict__ usage0,
               const float* __restrict__ PpE, const float* __restrict__ be,
               const float* __restrict__ PpA, const float* __restrict__ bad_,
               const float* __restrict__ mem0, float* __restrict__ out)
{
    __shared__ float wg[TSTEPS][SLOTS];
    const int tid = threadIdx.x;

    if (tid < 64){   // ---- phase A: sequential softmax/usage scan (wave 0) ----
        const int PS = TSTEPS * SLOTS;
        float u[4], bv[4], cur[4];
        #pragma unroll
        for (int c = 0; c < 4; ++c){
            const int sl = tid + 64 * c;
            u[c]  = usage0[sl];
            bv[c] = ba[sl];
            float sv = bv[c];
            #pragma unroll
            for (int p = 0; p < KQ; ++p) sv += PpL[p * PS + sl];
            cur[c] = sv;
        }
        for (int t = 0; t < TSTEPS; ++t){
            float nxt[4] = {0.f, 0.f, 0.f, 0.f};
            if (t < TSTEPS - 1){
                #pragma unroll
                for (int c = 0; c < 4; ++c){
                    const int sl = (t + 1) * SLOTS + tid + 64 * c;
                    float sv = bv[c];
                    #pragma unroll
                    for (int p = 0; p < KQ; ++p) sv += PpL[p * PS + sl];
                    nxt[c] = sv;
                }
            }
            float e[4];
            #pragma unroll
            for (int c = 0; c < 4; ++c) e[c] = __expf(cur[c] - 0.1f * u[c]);
            float sm_ = (e[0] + e[1]) + (e[2] + e[3]);
            #pragma unroll
            for (int off = 1; off < 64; off <<= 1) sm_ += __shfl_xor(sm_, off, 64);
            float inv = 1.0f / sm_;
            #pragma unroll
            for (int c = 0; c < 4; ++c){
                float ww = e[c] * inv;
                u[c] += ww;
                wg[t][tid + 64 * c] = ww;
            }
            #pragma unroll
            for (int c = 0; c < 4; ++c) cur[c] = nxt[c];
        }
    }
    __syncthreads();

    // ---- phase B: E/A partial-combine + memory recurrence ----
    const int s = tid;
    const int d0 = (int)blockIdx.x * 8;
    float b_e[8], b_a[8];
    *(float4*)(b_e)     = *(const float4*)(be + d0);
    *(float4*)(b_e + 4) = *(const float4*)(be + d0 + 4);
    *(float4*)(b_a)     = *(const float4*)(bad_ + d0);
    *(float4*)(b_a + 4) = *(const float4*)(bad_ + d0 + 4);
    float m[8];
    *(float4*)(m)     = *(const float4*)(mem0 + (size_t)s * DIM + d0);
    *(float4*)(m + 4) = *(const float4*)(mem0 + (size_t)s * DIM + d0 + 4);
    for (int t = 0; t < TSTEPS; ++t){
        const size_t ro = (size_t)t * DIM + d0;
        float e8[8], a8[8], tmp[8];
        *(float4*)(e8)     = *(const float4*)(PpE + ro);
        *(float4*)(e8 + 4) = *(const float4*)(PpE + ro + 4);
        *(float4*)(a8)     = *(const float4*)(PpA + ro);
        *(float4*)(a8 + 4) = *(const float4*)(PpA + ro + 4);
        #pragma unroll
        for (int p = 1; p < KQ; ++p){
            *(float4*)(tmp)     = *(const float4*)(PpE + (size_t)p * FB + ro);
            *(float4*)(tmp + 4) = *(const float4*)(PpE + (size_t)p * FB + ro + 4);
            #pragma unroll
            for (int c = 0; c < 8; ++c) e8[c] += tmp[c];
            *(float4*)(tmp)     = *(const float4*)(PpA + (size_t)p * FB + ro);
            *(float4*)(tmp + 4) = *(const float4*)(PpA + (size_t)p * FB + ro + 4);
            #pragma unroll
            for (int c = 0; c < 8; ++c) a8[c] += tmp[c];
        }
        float wq = 0.5f * wg[t][s];
        #pragma unroll
        for (int c = 0; c < 8; ++c){
            float er = sigmoidf_(e8[c] + b_e[c]);
            float ad = a8[c] + b_a[c];
            float f = wq * er;
            float tmp2 = fmaf(-f, m[c], m[c]);
            m[c] = fmaf(wq, ad, tmp2);
        }
    }
    float* op = out + (size_t)s * DIM + d0;
    *(float4*)(op)     = *(const float4*)(m);
    *(float4*)(op + 4) = *(const float4*)(m + 4);
}

extern "C" void kernel_launch(void* const* d_in, const int* in_sizes, int n_in,
                              void* d_out, int out_size, void* d_ws, size_t ws_size,
                              hipStream_t stream)
{
    const float* traces = (const float*)d_in[0];
    const float* noise  = (const float*)d_in[1];
    const float* mem0   = (const float*)d_in[2];
    const float* usage0 = (const float*)d_in[3];
    const float* W1 = (const float*)d_in[4];  const float* b1 = (const float*)d_in[5];
    const float* W2 = (const float*)d_in[6];  const float* b2 = (const float*)d_in[7];
    const float* Wl = (const float*)d_in[8];  const float* bl = (const float*)d_in[9];
    const float* vw = (const float*)d_in[10]; const float* vb = (const float*)d_in[11];
    const float* Wg = (const float*)d_in[12]; const float* bg = (const float*)d_in[13];
    const float* Wa = (const float*)d_in[14]; const float* ba = (const float*)d_in[15];
    const float* We = (const float*)d_in[16]; const float* be = (const float*)d_in[17];
    const float* Wad = (const float*)d_in[18]; const float* bad_ = (const float*)d_in[19];
    const int* idx = (const int*)d_in[20];

    float* pool = (float*)d_ws;
    float* Hv  = pool + 0 * (size_t)FB;
    float* Xv  = pool + 1 * (size_t)FB;
    float* LVv = pool + 2 * (size_t)FB;
    float* Gv  = pool + 3 * (size_t)FB;
    float* Pp  = pool + 4 * (size_t)FB;          // 8*FB stage partials
    float* PpE = pool + 12 * (size_t)FB;         // 8*FB
    float* PpA = pool + 20 * (size_t)FB;         // 8*FB
    float* PpL = pool + 28 * (size_t)FB;         // 8*64*256 = 1*FB

    gemm_g1<<<64 * KQ, 256, 0, stream>>>(traces, noise, idx, W1, Pp);
    comb8<0><<<64, 256, 0, stream>>>(Pp, b1, nullptr, nullptr, nullptr, Hv);
    gemm_s<<<64 * KQ, 256, 0, stream>>>(Hv, W2, Pp);
    comb8<1><<<64, 256, 0, stream>>>(Pp, b2, nullptr, nullptr, nullptr, Xv);
    gemm_s<<<64 * KQ, 256, 0, stream>>>(Xv, Wl, Pp);
    comb8<2><<<64, 256, 0, stream>>>(Pp, bl, vw, vb, nullptr, LVv);
    gemm_s<<<64 * KQ, 256, 0, stream>>>(LVv, Wg, Pp);
    comb8<3><<<64, 256, 0, stream>>>(Pp, bg, nullptr, nullptr, Xv, Gv);

    gemm_h<<<136 * KQ, 256, 0, stream>>>(Gv, We, Wad, Wa, PpE, PpA, PpL);
    memscan_k<<<DIM / 8, 256, 0, stream>>>(PpL, ba, usage0, PpE, be, PpA, bad_,
                                           mem0, (float*)d_out);
}

// Round 4
// 310.115 us; speedup vs baseline: 1.3440x; 1.3440x over previous
//
#include <hip/hip_runtime.h>
#include <math.h>

#define DIM 2048
#define SLOTS 256
#define TSTEPS 64
#define FB (TSTEPS * DIM)          // 131072 floats
#define KQ 8                       // K-split factor: K/block = 256
#define KS (DIM / KQ)              // 256 k-cols per block
#define BK 64                      // k-chunk per compute iteration
#define NC (KS / BK)               // 4 chunks
#define JG 32                      // j-cols per block (2 tiles of 16)

typedef unsigned short u16;
typedef __bf16 bf16x8 __attribute__((ext_vector_type(8)));
typedef float f32x4 __attribute__((ext_vector_type(4)));

union FragU { unsigned u[4]; bf16x8 v; };

__device__ __forceinline__ u16 f2bf(float f){
    union { float f; unsigned u; } v; v.f = f;
    unsigned r = v.u + 0x7fffu + ((v.u >> 16) & 1u);
    return (u16)(r >> 16);
}
__device__ __forceinline__ float sigmoidf_(float x){ return 1.0f / (1.0f + __expf(-x)); }

__device__ __forceinline__ void split8t(const float* x, bf16x8& hi, bf16x8& lo){
    FragU H, L;
    #pragma unroll
    for (int p = 0; p < 4; ++p){
        union { float f; unsigned u; } u0, u1, l0, l1;
        u0.f = x[2*p]; u1.f = x[2*p+1];
        unsigned h0 = u0.u & 0xffff0000u, h1 = u1.u & 0xffff0000u;
        H.u[p] = (h0 >> 16) | h1;
        l0.f = u0.f - __uint_as_float(h0);
        l1.f = u1.f - __uint_as_float(h1);
        L.u[p] = (l0.u >> 16) | (l1.u & 0xffff0000u);
    }
    hi = H.v; lo = L.v;
}

__device__ __forceinline__ f32x4 mfma16(bf16x8 a, bf16x8 b, f32x4 c){
    return __builtin_amdgcn_mfma_f32_16x16x32_bf16(a, b, c, 0, 0, 0);
}

// async global->LDS, 16B/lane; lds base wave-uniform, lane i lands at +i*16
__device__ __forceinline__ void gl_lds16(const float* gp, float* lp){
    __builtin_amdgcn_global_load_lds(
        (const __attribute__((address_space(1))) unsigned int*)gp,
        (__attribute__((address_space(3))) unsigned int*)lp, 16, 0, 0);
}

// ---- inline MFMA D-layout calibration (2 MFMAs, per block) ----
__device__ __forceinline__ void calib_inline(int lane, int w, int* trr, int* jrr){
    const u16 oneb = 0x3F80;
    const u16 lb = f2bf((float)((lane & 15) + 1));
    FragU O, L;
    #pragma unroll
    for (int p = 0; p < 4; ++p){
        O.u[p] = ((unsigned)oneb) | (((unsigned)oneb) << 16);
        L.u[p] = ((unsigned)lb)   | (((unsigned)lb)   << 16);
    }
    f32x4 z = {0.f, 0.f, 0.f, 0.f};
    f32x4 dj = mfma16(O.v, L.v, z);
    f32x4 dt = mfma16(L.v, O.v, z);
    #pragma unroll
    for (int r = 0; r < 4; ++r){
        int jl = (int)(dj[r] * (1.0f/32.0f) + 0.5f) - 1;
        int tl = (int)(dt[r] * (1.0f/32.0f) + 0.5f) - 1;
        trr[r] = w * 16 + (tl & 15);
        jrr[r] = jl & 15;
    }
}

// LDS: A-slice [4 chunks][64 rows][BK] (64 KB, staged once) + W ring 2x[16][BK] (8 KB).
struct GSm { float A[NC * 64 * BK]; float Wb[2][16 * BK]; };

__device__ __forceinline__ const float* waddr(const float* Wg0, int kbase, int chunk,
                                              int w, int rsub, int s){
    const int rowL = w * 4 + rsub;           // 0..15
    const int nj = chunk >> 2, ncc = chunk & 3;
    return Wg0 + (size_t)(nj * 16 + rowL) * DIM + kbase + ncc * BK + ((s ^ rowL) << 2);
}

// ---------------- A-resident, reg-staged 4-deep W-pipelined GEMM core ----------------
// GATHER=1: A-slice computed on the fly from traces[idx]+0.01*noise (stage-1 fusion).
template<int GATHER>
__device__ __forceinline__ void gemm_core(const float* __restrict__ A,
    const float* __restrict__ traces, const float* __restrict__ noise,
    const int* __restrict__ idxw, int i64f,
    const float* __restrict__ Wg0, int kq, GSm& sm, f32x4* acc)
{
    const int tid = threadIdx.x;
    const int lane = tid & 63, w = tid >> 6;
    const int s = lane & 15, rsub = lane >> 4;
    const int n4 = lane & 15;
    const int kbase = kq * KS;

    // ---- A-stage (once) ----
    if (GATHER){
        #pragma unroll
        for (int i = 0; i < 4; ++i){
            const int rowL = w * 16 + i * 4 + rsub;
            long rg = i64f ? (long)idxw[2 * rowL] : (long)idxw[rowL];
            const float* tp = traces + (size_t)rg * DIM + kbase + ((s ^ (rowL & 15)) << 2);
            const float* np = noise + (size_t)rowL * DIM + kbase + ((s ^ (rowL & 15)) << 2);
            #pragma unroll
            for (int c = 0; c < NC; ++c){
                float4 tv = *(const float4*)(tp + c * BK);
                float4 nv = *(const float4*)(np + c * BK);
                float4 r;
                r.x = fmaf(0.01f, nv.x, tv.x); r.y = fmaf(0.01f, nv.y, tv.y);
                r.z = fmaf(0.01f, nv.z, tv.z); r.w = fmaf(0.01f, nv.w, tv.w);
                *(float4*)&sm.A[(c * 64 + rowL) * BK + s * 4] = r;
            }
        }
    } else {
        #pragma unroll
        for (int c = 0; c < NC; ++c)
            #pragma unroll
            for (int i = 0; i < 4; ++i){
                const int rowL = w * 16 + i * 4 + rsub;
                const float* gp = A + (size_t)rowL * DIM + kbase + c * BK + ((s ^ (rowL & 15)) << 2);
                gl_lds16(gp, sm.A + (c * 64 + w * 16 + i * 4) * BK);
            }
    }
    // ---- W prologue: chunks 0..3 into a 4-reg ring ----
    float4 wreg[4];
    #pragma unroll
    for (int k = 0; k < 4; ++k)
        wreg[k] = *(const float4*)waddr(Wg0, kbase, k, w, rsub, s);
    __syncthreads();            // full drain once: A staged, wreg 0..3 resident

    acc[0] = (f32x4){0.f, 0.f, 0.f, 0.f};
    acc[1] = (f32x4){0.f, 0.f, 0.f, 0.f};

    // 8 chunk-iterations; write W chunk `it` from reg ring, reload ring slot with
    // chunk it+4 (plain VMEM loads stay in flight across the raw barriers — the
    // compiler inserts the counted vmcnt wait before the dependent ds_write).
    #pragma unroll
    for (int it = 0; it < 2 * NC; ++it){
        const int lslot = it & 1;      // LDS W buffer
        const int rslot = it & 3;      // reg ring slot (static after unroll)
        *(float4*)&sm.Wb[lslot][(w * 4 + rsub) * BK + s * 4] = wreg[rslot];
        if (it + 4 < 2 * NC)
            wreg[rslot] = *(const float4*)waddr(Wg0, kbase, it + 4, w, rsub, s);
        asm volatile("s_waitcnt lgkmcnt(0)\n\ts_barrier" ::: "memory");
        const int jt = it >> 2, c = it & 3;
        const float* At = sm.A + c * 64 * BK;
        const float* Wt = sm.Wb[lslot];
        #pragma unroll
        for (int ks = 0; ks < 2; ++ks){
            const int cg0 = ks * 8 + (lane >> 4) * 2;
            const int rA = w * 16 + n4;
            float a8[8], w8[8];
            *(float4*)(a8)     = *(const float4*)&At[rA * BK + ((cg0 ^ n4) << 2)];
            *(float4*)(a8 + 4) = *(const float4*)&At[rA * BK + (((cg0 + 1) ^ n4) << 2)];
            *(float4*)(w8)     = *(const float4*)&Wt[n4 * BK + ((cg0 ^ n4) << 2)];
            *(float4*)(w8 + 4) = *(const float4*)&Wt[n4 * BK + (((cg0 + 1) ^ n4) << 2)];
            bf16x8 ah, al, wh, wl;
            split8t(a8, ah, al);
            split8t(w8, wh, wl);
            if (jt == 0){
                acc[0] = mfma16(ah, wh, acc[0]);
                acc[0] = mfma16(al, wh, acc[0]);
                acc[0] = mfma16(ah, wl, acc[0]);
            } else {
                acc[1] = mfma16(ah, wh, acc[1]);
                acc[1] = mfma16(al, wh, acc[1]);
                acc[1] = mfma16(ah, wl, acc[1]);
            }
        }
        asm volatile("s_barrier" ::: "memory");  // reads done before next overwrite
    }
}

// stage-1 GEMM with fused gather/noise prep: grid = 64 jg x 8 kq
__global__ __launch_bounds__(256)
void gemm_g1(const float* __restrict__ traces, const float* __restrict__ noise,
             const int* __restrict__ idxw, const float* __restrict__ W,
             float* __restrict__ Pp)
{
    __shared__ GSm sm;
    __shared__ int i64f_s;
    const int tid = threadIdx.x;
    int v = 0;
    if (tid < 32) v = (idxw[2 * tid + 1] != 0) ? 1 : 0;
    unsigned long long bm = __ballot(v);
    if (tid == 0) i64f_s = (bm == 0ull) ? 1 : 0;
    __syncthreads();
    const int i64f = i64f_s;

    const int kq = blockIdx.x & (KQ - 1);
    const int jg = blockIdx.x >> 3;
    const int j0 = jg * JG;
    const int lane = tid & 63, w = tid >> 6;
    int trr[4], jrr[4];
    calib_inline(lane, w, trr, jrr);
    f32x4 acc[2];
    gemm_core<1>(nullptr, traces, noise, idxw, i64f, W + (size_t)j0 * DIM, kq, sm, acc);
    float* outb = Pp + (size_t)kq * FB;
    #pragma unroll
    for (int jt = 0; jt < 2; ++jt)
        #pragma unroll
        for (int r = 0; r < 4; ++r)
            outb[(size_t)trr[r] * DIM + j0 + jt * 16 + jrr[r]] = acc[jt][r];
}

// stage GEMM: grid = 64 jg x 8 kq = 512
__global__ __launch_bounds__(256)
void gemm_s(const float* __restrict__ A, const float* __restrict__ W,
            float* __restrict__ Pp)
{
    __shared__ GSm sm;
    const int kq = blockIdx.x & (KQ - 1);
    const int jg = blockIdx.x >> 3;
    const int j0 = jg * JG;
    const int lane = threadIdx.x & 63, w = threadIdx.x >> 6;
    int trr[4], jrr[4];
    calib_inline(lane, w, trr, jrr);
    f32x4 acc[2];
    gemm_core<0>(A, nullptr, nullptr, nullptr, 0, W + (size_t)j0 * DIM, kq, sm, acc);
    float* outb = Pp + (size_t)kq * FB;
    #pragma unroll
    for (int jt = 0; jt < 2; ++jt)
        #pragma unroll
        for (int r = 0; r < 4; ++r)
            outb[(size_t)trr[r] * DIM + j0 + jt * 16 + jrr[r]] = acc[jt][r];
}

// heads GEMM: grid = (64 We + 64 Wad + 8 Wa) x 8 kq = 1088
__global__ __launch_bounds__(256)
void gemm_h(const float* __restrict__ G,
            const float* __restrict__ We, const float* __restrict__ Wad,
            const float* __restrict__ Wa,
            float* __restrict__ PpE, float* __restrict__ PpA, float* __restrict__ PpL)
{
    __shared__ GSm sm;
    const int kq = blockIdx.x & (KQ - 1);
    const int jg = blockIdx.x >> 3;
    const float* W; float* out; int j0, NJ;
    if (jg < 64)       { W = We;  out = PpE; j0 = jg * JG;        NJ = DIM; }
    else if (jg < 128) { W = Wad; out = PpA; j0 = (jg - 64) * JG; NJ = DIM; }
    else               { W = Wa;  out = PpL; j0 = (jg - 128) * JG; NJ = SLOTS; }
    const int lane = threadIdx.x & 63, w = threadIdx.x >> 6;
    int trr[4], jrr[4];
    calib_inline(lane, w, trr, jrr);
    f32x4 acc[2];
    gemm_core<0>(G, nullptr, nullptr, nullptr, 0, W + (size_t)j0 * DIM, kq, sm, acc);
    float* outb = out + (size_t)kq * 64 * NJ;
    #pragma unroll
    for (int jt = 0; jt < 2; ++jt)
        #pragma unroll
        for (int r = 0; r < 4; ++r)
            outb[(size_t)trr[r] * NJ + j0 + jt * 16 + jrr[r]] = acc[jt][r];
}

// ---------------- combine 8 partials + bias + activation (NJ = DIM) ----------------
// MODE 0: relu  1: plain  2: sig(u)*sig(ps*vw+vb)  3: X*sig(u)  4: sigmoid
template<int MODE>
__device__ __forceinline__ void comb_core(int bb, const float* __restrict__ P,
    const float* __restrict__ bias, const float* __restrict__ vwp,
    const float* __restrict__ vbp, const float* __restrict__ Xp,
    float* __restrict__ out)
{
    const size_t i0 = ((size_t)bb * 256 + threadIdx.x) * 8;
    const int t = (int)(i0 >> 11);
    const int j = (int)(i0 & (DIM - 1));
    float v[8], tmp[8];
    *(float4*)(v)     = *(const float4*)(P + i0);
    *(float4*)(v + 4) = *(const float4*)(P + i0 + 4);
    #pragma unroll
    for (int p = 1; p < KQ; ++p){
        *(float4*)(tmp)     = *(const float4*)(P + (size_t)p * FB + i0);
        *(float4*)(tmp + 4) = *(const float4*)(P + (size_t)p * FB + i0 + 4);
        #pragma unroll
        for (int c = 0; c < 8; ++c) v[c] += tmp[c];
    }
    float b8[8];
    *(float4*)(b8)     = *(const float4*)(bias + j);
    *(float4*)(b8 + 4) = *(const float4*)(bias + j + 4);
    float x8[8], y8[8];
    if (MODE == 2){
        *(float4*)(x8)     = *(const float4*)(vwp + j);
        *(float4*)(x8 + 4) = *(const float4*)(vwp + j + 4);
        *(float4*)(y8)     = *(const float4*)(vbp + j);
        *(float4*)(y8 + 4) = *(const float4*)(vbp + j + 4);
    }
    if (MODE == 3){
        *(float4*)(x8)     = *(const float4*)(Xp + i0);
        *(float4*)(x8 + 4) = *(const float4*)(Xp + i0 + 4);
    }
    const float ps = -cosf(0.37699111843077515f * (float)(t + 1));
    float r[8];
    #pragma unroll
    for (int c = 0; c < 8; ++c){
        float u = v[c] + b8[c];
        if (MODE == 0)      r[c] = fmaxf(u, 0.f);
        else if (MODE == 1) r[c] = u;
        else if (MODE == 2) r[c] = sigmoidf_(u) * sigmoidf_(fmaf(ps, x8[c], y8[c]));
        else if (MODE == 3) r[c] = x8[c] * sigmoidf_(u);
        else                r[c] = sigmoidf_(u);
    }
    *(float4*)(out + i0)     = *(const float4*)(r);
    *(float4*)(out + i0 + 4) = *(const float4*)(r + 4);
}

template<int MODE>
__global__ __launch_bounds__(256)
void comb8(const float* __restrict__ P, const float* __restrict__ bias,
           const float* __restrict__ vwp, const float* __restrict__ vbp,
           const float* __restrict__ Xp, float* __restrict__ out)
{
    comb_core<MODE>((int)blockIdx.x, P, bias, vwp, vbp, Xp, out);
}

// ------ fused tail 1: E-combine (0-63) + A-combine (64-127) + L-combine+scan (128) ----
__global__ __launch_bounds__(256)
void comb_eal_scan(const float* __restrict__ PpE, const float* __restrict__ be,
                   const float* __restrict__ PpA, const float* __restrict__ bad_,
                   const float* __restrict__ PpL, const float* __restrict__ ba,
                   const float* __restrict__ usage0,
                   float* __restrict__ ER, float* __restrict__ AD,
                   float* __restrict__ WG)
{
    __shared__ float ls[TSTEPS * SLOTS];   // 64 KB (block 128 only)
    const int b = (int)blockIdx.x;
    if (b < 64){
        comb_core<4>(b, PpE, be, nullptr, nullptr, nullptr, ER);
        return;
    }
    if (b < 128){
        comb_core<1>(b - 64, PpA, bad_, nullptr, nullptr, nullptr, AD);
        return;
    }
    // ---- block 128: parallel 8-partial logit combine (+ba) into LDS ----
    const int tid = threadIdx.x;
    const int PS = TSTEPS * SLOTS;
    #pragma unroll
    for (int i = 0; i < 16; ++i){
        const int li = (i * 256 + tid) * 4;          // element index, float4-aligned
        float sv[4], tmp[4];
        *(float4*)(sv) = *(const float4*)(ba + (li & (SLOTS - 1)));
        #pragma unroll
        for (int p = 0; p < KQ; ++p){
            *(float4*)(tmp) = *(const float4*)(PpL + (size_t)p * PS + li);
            #pragma unroll
            for (int c = 0; c < 4; ++c) sv[c] += tmp[c];
        }
        *(float4*)&ls[li] = *(const float4*)(sv);
    }
    __syncthreads();
    // ---- wave 0: sequential softmax/usage scan from LDS ----
    if (tid >= 64) return;
    float u[4];
    #pragma unroll
    for (int c = 0; c < 4; ++c) u[c] = usage0[tid + 64 * c];
    for (int t = 0; t < TSTEPS; ++t){
        float e[4];
        #pragma unroll
        for (int c = 0; c < 4; ++c)
            e[c] = __expf(ls[t * SLOTS + tid + 64 * c] - 0.1f * u[c]);
        float sm_ = (e[0] + e[1]) + (e[2] + e[3]);
        #pragma unroll
        for (int off = 1; off < 64; off <<= 1) sm_ += __shfl_xor(sm_, off, 64);
        float inv = 1.0f / sm_;
        float* wr = WG + t * SLOTS;
        #pragma unroll
        for (int c = 0; c < 4; ++c){
            float ww = e[c] * inv;
            u[c] += ww;
            wr[tid + 64 * c] = ww;
        }
    }
}

// ---------------- tail 2: memory recurrence (combined ER/AD + WG) ----------------
__global__ __launch_bounds__(256)
void mem_k(const float* __restrict__ mem0, const float* __restrict__ wgt,
           const float* __restrict__ ER, const float* __restrict__ AD,
           float* __restrict__ out)
{
    const int s = threadIdx.x;
    const int d0 = blockIdx.x * 8;
    float m[8];
    *(float4*)(m)     = *(const float4*)(mem0 + (size_t)s * DIM + d0);
    *(float4*)(m + 4) = *(const float4*)(mem0 + (size_t)s * DIM + d0 + 4);
    for (int t = 0; t < TSTEPS; ++t){
        const size_t ro = (size_t)t * DIM + d0;
        float e8[8], a8[8];
        *(float4*)(e8)     = *(const float4*)(ER + ro);
        *(float4*)(e8 + 4) = *(const float4*)(ER + ro + 4);
        *(float4*)(a8)     = *(const float4*)(AD + ro);
        *(float4*)(a8 + 4) = *(const float4*)(AD + ro + 4);
        float w = 0.5f * wgt[t * SLOTS + s];
        #pragma unroll
        for (int c = 0; c < 8; ++c){
            float f = w * e8[c];
            float tmp = fmaf(-f, m[c], m[c]);
            m[c] = fmaf(w, a8[c], tmp);
        }
    }
    float* op = out + (size_t)s * DIM + d0;
    *(float4*)(op)     = *(const float4*)(m);
    *(float4*)(op + 4) = *(const float4*)(m + 4);
}

extern "C" void kernel_launch(void* const* d_in, const int* in_sizes, int n_in,
                              void* d_out, int out_size, void* d_ws, size_t ws_size,
                              hipStream_t stream)
{
    const float* traces = (const float*)d_in[0];
    const float* noise  = (const float*)d_in[1];
    const float* mem0   = (const float*)d_in[2];
    const float* usage0 = (const float*)d_in[3];
    const float* W1 = (const float*)d_in[4];  const float* b1 = (const float*)d_in[5];
    const float* W2 = (const float*)d_in[6];  const float* b2 = (const float*)d_in[7];
    const float* Wl = (const float*)d_in[8];  const float* bl = (const float*)d_in[9];
    const float* vw = (const float*)d_in[10]; const float* vb = (const float*)d_in[11];
    const float* Wg = (const float*)d_in[12]; const float* bg = (const float*)d_in[13];
    const float* Wa = (const float*)d_in[14]; const float* ba = (const float*)d_in[15];
    const float* We = (const float*)d_in[16]; const float* be = (const float*)d_in[17];
    const float* Wad = (const float*)d_in[18]; const float* bad_ = (const float*)d_in[19];
    const int* idx = (const int*)d_in[20];

    float* pool = (float*)d_ws;
    float* Hv  = pool + 0 * (size_t)FB;
    float* Xv  = pool + 1 * (size_t)FB;
    float* LVv = pool + 2 * (size_t)FB;
    float* Gv  = pool + 3 * (size_t)FB;
    float* ERv = pool + 4 * (size_t)FB;
    float* ADv = pool + 5 * (size_t)FB;
    float* Pp  = pool + 6 * (size_t)FB;          // 8*FB stage partials
    float* PpE = pool + 14 * (size_t)FB;         // 8*FB
    float* PpA = pool + 22 * (size_t)FB;         // 8*FB
    float* PpL = pool + 30 * (size_t)FB;         // 8*64*256 = 1*FB
    float* WGv = pool + 31 * (size_t)FB;         // 64*256

    gemm_g1<<<64 * KQ, 256, 0, stream>>>(traces, noise, idx, W1, Pp);
    comb8<0><<<64, 256, 0, stream>>>(Pp, b1, nullptr, nullptr, nullptr, Hv);
    gemm_s<<<64 * KQ, 256, 0, stream>>>(Hv, W2, Pp);
    comb8<1><<<64, 256, 0, stream>>>(Pp, b2, nullptr, nullptr, nullptr, Xv);
    gemm_s<<<64 * KQ, 256, 0, stream>>>(Xv, Wl, Pp);
    comb8<2><<<64, 256, 0, stream>>>(Pp, bl, vw, vb, nullptr, LVv);
    gemm_s<<<64 * KQ, 256, 0, stream>>>(LVv, Wg, Pp);
    comb8<3><<<64, 256, 0, stream>>>(Pp, bg, nullptr, nullptr, Xv, Gv);

    gemm_h<<<136 * KQ, 256, 0, stream>>>(Gv, We, Wad, Wa, PpE, PpA, PpL);
    comb_eal_scan<<<129, 256, 0, stream>>>(PpE, be, PpA, bad_, PpL, ba, usage0,
                                           ERv, ADv, WGv);
    mem_k<<<DIM / 8, 256, 0, stream>>>(mem0, WGv, ERv, ADv, (float*)d_out);
}